// Round 3
// baseline (1241.318 us; speedup 1.0000x reference)
//
#include <hip/hip_runtime.h>

// VQ codebook assignment via split-f16 MFMA GEMM, pre-swizzled panels + global_load_lds.
//   x:       [B=32, C=256, H=32, W=32] f32   -> tokens [32768][256]
//   embed_w: [K=2048, C=256] f32
// out f32: quantize [32,256,32,32] (8388608) | embed_index [32,32,32] (32768 as float) | loss [1]=0
//
// Math (verified R2): e' = 8192*e; eh=f16(e'), el=f16((e'-eh)*4096); xh=f16(x), xl=f16((x-xh)*4096).
//   8192*dot = acc1 + acc2/4096,  acc1 = sum xh*eh, acc2 = sum(xh*el + xl*eh)
//   d' = 8192*esq - 2*acc1 - 2^-11*acc2 ; argmin_k d' == argmin_k (esq - 2 dot)  (err ~2^-24 rel)
//
// ws panel layout (the exact LDS image global_load_lds fills linearly):
//   A: [panel 256][kc 8][limb 2][slot 4][row 128][16B]   (128 tokens/panel, 32 ch/chunk) = 32 MB
//   E: [panel 16 ][kc 8][limb 2][slot 4][row 128][16B]   (128 codes/panel)               =  2 MB
// slot g holds channels kc*32 + g*8 .. +7 — matches the mfma_16x16x32 A/B lane layout
// (lane l reads row l&15, k-block (l>>4)*8). Rows stride 16B -> ds_read_b128 is 2-way max.

#define CDIM 256
#define KDIM 2048
#define HW   1024
#define NTOK 32768
#define QOFF 8388608
#define LOFF (QOFF + NTOK)

typedef _Float16 f16x8 __attribute__((ext_vector_type(8)));
typedef float    f32x4 __attribute__((ext_vector_type(4)));

__device__ __forceinline__ void gll16(const void* g, void* l) {
    __builtin_amdgcn_global_load_lds(
        (const __attribute__((address_space(1))) unsigned int*)g,
        (__attribute__((address_space(3))) unsigned int*)l, 16, 0, 0);
}

// ---------------- prep E: limbs into panel image + scaled esq + loss ----------------
__global__ __launch_bounds__(256) void prep_e_kernel(const float* __restrict__ ew,
                                                     char* __restrict__ Ews,
                                                     float* __restrict__ esq,
                                                     float* __restrict__ out) {
    const int t = threadIdx.x;
    const int code = blockIdx.x * 8 + (t >> 5);   // 256 blocks x 8 codes
    const int u = t & 31;                          // 8-channel unit
    const float4 v0 = *(const float4*)&ew[(size_t)code * CDIM + u * 8];
    const float4 v1 = *(const float4*)&ew[(size_t)code * CDIM + u * 8 + 4];
    float s = v0.x*v0.x + v0.y*v0.y + v0.z*v0.z + v0.w*v0.w
            + v1.x*v1.x + v1.y*v1.y + v1.z*v1.z + v1.w*v1.w;
    #pragma unroll
    for (int m = 16; m >= 1; m >>= 1) s += __shfl_xor(s, m, 32);
    if (u == 0) esq[code] = s * 8192.0f;
    const float e[8] = {v0.x, v0.y, v0.z, v0.w, v1.x, v1.y, v1.z, v1.w};
    union { _Float16 h[8]; uint4 q; } H, L;
    #pragma unroll
    for (int j = 0; j < 8; ++j) {
        const float ev = e[j] * 8192.0f;
        const _Float16 hh = (_Float16)ev;
        H.h[j] = hh;
        L.h[j] = (_Float16)((ev - (float)hh) * 4096.0f);
    }
    const int kc = u >> 2, g = u & 3;
    const int cp = code >> 7, row = code & 127;
    char* d = Ews + (size_t)cp * 131072 + kc * 16384 + (g * 128 + row) * 16;
    *(uint4*)d = H.q;
    *(uint4*)(d + 8192) = L.q;
    if (blockIdx.x == 0 && t == 0) out[LOFF] = 0.0f;
}

// ---------------- prep X: transpose [C][HW] -> limb panel image ----------------
__global__ __launch_bounds__(256) void prep_x_kernel(const float* __restrict__ x,
                                                     char* __restrict__ Aws) {
    __shared__ float tile[32][257];
    const int bid = blockIdx.x;              // 32 b * 8 kc * 4 hwblk = 1024
    const int b = bid >> 5;
    const int kc = (bid >> 2) & 7;
    const int c0 = kc * 32;
    const int hw0 = (bid & 3) * 256;
    const int t = threadIdx.x;
    #pragma unroll 8
    for (int r = 0; r < 32; ++r)
        tile[r][t] = x[((size_t)(b * CDIM + c0 + r) << 10) + hw0 + t];
    __syncthreads();
    union { _Float16 h[32]; uint4 q[4]; } Hb, Lb;
    #pragma unroll 8
    for (int r = 0; r < 32; ++r) {
        const float xv = tile[r][t];
        const _Float16 hh = (_Float16)xv;
        Hb.h[r] = hh;
        Lb.h[r] = (_Float16)((xv - (float)hh) * 4096.0f);
    }
    const int tok = b * HW + hw0 + t;
    const int p = tok >> 7, row = tok & 127;
    char* d = Aws + (size_t)p * 131072 + kc * 16384 + row * 16;
    #pragma unroll
    for (int g = 0; g < 4; ++g) {
        *(uint4*)(d + g * 2048)        = Hb.q[g];   // high limb
        *(uint4*)(d + 8192 + g * 2048) = Lb.q[g];   // low limb
    }
}

// ---------------- fused MFMA GEMM + argmin ----------------
// 128x128 tile, 4 waves (2x2 of 64x64), BK=32, 32KB LDS -> 5 blocks/CU.
__global__ __launch_bounds__(256, 5) void vqmm_kernel(const char* __restrict__ Aws,
                                                      const char* __restrict__ Ews,
                                                      const float* __restrict__ esq,
                                                      float* __restrict__ cv,
                                                      int* __restrict__ ci) {
    __shared__ __align__(16) char smem[32768];   // Ah 8K | Al 8K | Eh 8K | El 8K

    const int t = threadIdx.x;
    const int bid = blockIdx.x;
    // XCD-grouped swizzle: the 16 bx-blocks of one by share bid%8 -> same XCD (A panel L2-local)
    const int by = (bid & 7) | ((bid >> 7) << 3);   // token panel 0..255
    const int bx = (bid >> 3) & 15;                 // code panel 0..15
    const int lane = t & 63, w = t >> 6;
    const int wm = w >> 1, wn = w & 1;
    const int g = lane >> 4, lr = lane & 15;

    // staging role: wave 0->Ah, 1->Al, 2->Eh, 3->El ; 8 x 1KB issues per chunk
    const int limb = w & 1;
    const char* src = ((w < 2) ? (Aws + (size_t)by * 131072) : (Ews + (size_t)bx * 131072))
                      + limb * 8192 + lane * 16;
    const int ldsb = ((w < 2) ? 0 : 16384) + limb * 8192;

    const f32x4 zf = {0.f, 0.f, 0.f, 0.f};
    f32x4 acc1[4][4], acc2[4][4];
    #pragma unroll
    for (int m = 0; m < 4; ++m)
        #pragma unroll
        for (int n = 0; n < 4; ++n) { acc1[m][n] = zf; acc2[m][n] = zf; }

    // prologue: stage chunk 0
    #pragma unroll
    for (int j = 0; j < 8; ++j)
        gll16(src + j * 1024, smem + ldsb + j * 1024);
    __syncthreads();

    const int aro = (g * 128 + wm * 64 + lr) * 16;            // Ah frag base
    const int bro = 16384 + (g * 128 + wn * 64 + lr) * 16;    // Eh frag base

    for (int kc = 0; kc < 8; ++kc) {
        f16x8 fa[4], fb[4], fc[4], fd[4];
        #pragma unroll
        for (int m = 0; m < 4; ++m) {
            fa[m] = *(const f16x8*)(smem + aro + m * 256);
            fb[m] = *(const f16x8*)(smem + 8192 + aro + m * 256);
        }
        #pragma unroll
        for (int n = 0; n < 4; ++n) {
            fc[n] = *(const f16x8*)(smem + bro + n * 256);
            fd[n] = *(const f16x8*)(smem + 8192 + bro + n * 256);
        }
        __syncthreads();                 // all waves' LDS reads of this chunk retired
        if (kc < 7) {                    // stage next chunk; latency hides under MFMA below
            const char* s2 = src + (kc + 1) * 16384;
            #pragma unroll
            for (int j = 0; j < 8; ++j)
                gll16(s2 + j * 1024, smem + ldsb + j * 1024);
        }
        __builtin_amdgcn_sched_barrier(0);   // keep load issues ahead of the MFMA cluster
        #pragma unroll
        for (int m = 0; m < 4; ++m)
            #pragma unroll
            for (int n = 0; n < 4; ++n) {
                acc1[m][n] = __builtin_amdgcn_mfma_f32_16x16x32_f16(fa[m], fc[n], acc1[m][n], 0, 0, 0);
                acc2[m][n] = __builtin_amdgcn_mfma_f32_16x16x32_f16(fa[m], fd[n], acc2[m][n], 0, 0, 0);
                acc2[m][n] = __builtin_amdgcn_mfma_f32_16x16x32_f16(fb[m], fc[n], acc2[m][n], 0, 0, 0);
            }
        __syncthreads();                 // staged chunk kc+1 visible (vmcnt drained here)
    }

    // epilogue (reuses smem): esq[128] at 0, sv[128][2] at 1024, si[128][2] at 2048
    float* s_esq = (float*)smem;
    float* sv = (float*)(smem + 1024);
    int*   si = (int*)(smem + 2048);
    if (t < 128) s_esq[t] = esq[bx * 128 + t];
    __syncthreads();
    #pragma unroll
    for (int m = 0; m < 4; ++m) {
        #pragma unroll
        for (int r = 0; r < 4; ++r) {
            float bv = 3.4e38f; int bi = 0x7fffffff;
            #pragma unroll
            for (int n = 0; n < 4; ++n) {
                const float d = fmaf(-2.0f, acc1[m][n][r],
                                fmaf(-4.8828125e-4f, acc2[m][n][r], s_esq[wn * 64 + n * 16 + lr]));
                const int cidx = bx * 128 + wn * 64 + n * 16 + lr;
                if (d < bv) { bv = d; bi = cidx; }
            }
            #pragma unroll
            for (int mk = 1; mk < 16; mk <<= 1) {
                const float ov = __shfl_xor(bv, mk, 16);
                const int   oi = __shfl_xor(bi, mk, 16);
                if (ov < bv || (ov == bv && oi < bi)) { bv = ov; bi = oi; }
            }
            if (lr == 0) {
                const int tl = wm * 64 + m * 16 + g * 4 + r;
                sv[tl * 2 + wn] = bv; si[tl * 2 + wn] = bi;
            }
        }
    }
    __syncthreads();
    if (t < 128) {
        const float v0 = sv[t * 2], v1 = sv[t * 2 + 1];
        const int   i0 = si[t * 2], i1 = si[t * 2 + 1];
        const bool swp = (v1 < v0) || (v1 == v0 && i1 < i0);
        const size_t o = (size_t)bx * NTOK + by * 128 + t;
        cv[o] = swp ? v1 : v0;
        ci[o] = swp ? i1 : i0;
    }
}

// ---------------- merge 16 candidates + gather quantize ----------------
__global__ __launch_bounds__(256) void merge_gather_kernel(const float* __restrict__ cv,
                                                           const int* __restrict__ ci,
                                                           const float* __restrict__ ew,
                                                           float* __restrict__ out) {
    __shared__ int sIdx[64];
    const int t = threadIdx.x;
    const int n0 = blockIdx.x * 64;
    if (t < 64) {
        const int tok = n0 + t;
        float bv = cv[tok]; int bi = ci[tok];
        #pragma unroll
        for (int s = 1; s < 16; ++s) {
            const float v = cv[(size_t)s * NTOK + tok];
            const int   i2 = ci[(size_t)s * NTOK + tok];
            if (v < bv || (v == bv && i2 < bi)) { bv = v; bi = i2; }
        }
        sIdx[t] = bi;
        out[QOFF + tok] = (float)bi;
    }
    __syncthreads();
    const int b = n0 >> 10, hw0 = n0 & (HW - 1);
    const int i = t & 63, cg = t >> 6;
    const int kidx = sIdx[i];
    const float* er = ew + (size_t)kidx * CDIM;
    float* ob = out + (size_t)b * CDIM * HW + hw0 + i;
    #pragma unroll
    for (int p = 0; p < CDIM / 4; ++p) {
        const int c = cg * 64 + p;
        ob[(size_t)c * HW] = er[c];
    }
}

extern "C" void kernel_launch(void* const* d_in, const int* in_sizes, int n_in,
                              void* d_out, int out_size, void* d_ws, size_t ws_size,
                              hipStream_t stream) {
    const float* x  = (const float*)d_in[0];
    const float* ew = (const float*)d_in[1];
    float* out = (float*)d_out;
    char* ws = (char*)d_ws;

    char*  Aws = ws;                                // 33,554,432 B
    char*  Ews = ws + 33554432;                     //  2,097,152 B
    float* esq = (float*)(ws + 35651584);           //      8,192 B
    float* cvv = (float*)(ws + 35659776);           //  2,097,152 B
    int*   cii = (int*)(ws + 37756928);             //  2,097,152 B

    prep_e_kernel<<<KDIM / 8, 256, 0, stream>>>(ew, Ews, esq, out);
    prep_x_kernel<<<1024, 256, 0, stream>>>(x, Aws);
    vqmm_kernel<<<4096, 256, 0, stream>>>(Aws, Ews, esq, cvv, cii);
    merge_gather_kernel<<<NTOK / 64, 256, 0, stream>>>(cvv, cii, ew, out);
}

// Round 4
// 339.310 us; speedup vs baseline: 3.6584x; 3.6584x over previous
//
#include <hip/hip_runtime.h>

// VQ codebook assignment via split-f16 MFMA GEMM, pre-swizzled linear panels, reg-staged LDS.
//   x:       [B=32, C=256, H=32, W=32] f32   -> tokens [32768][256]
//   embed_w: [K=2048, C=256] f32
// out f32: quantize [32,256,32,32] (8388608) | embed_index [32,32,32] (32768 as float) | loss [1]=0
//
// Math (verified R2/R3): e' = 8192*e; eh=f16(e'), el=f16((e'-eh)*4096); xh=f16(x), xl=f16((x-xh)*4096).
//   8192*dot = acc1 + acc2/4096,  acc1 = sum xh*eh, acc2 = sum(xh*el + xl*eh)
//   d' = 8192*esq - 2*acc1 - 2^-11*acc2 ; argmin_k d' == argmin_k (esq - 2 dot)  (err ~2^-24 rel)
//
// ws panel layout (linear LDS image, verified in R3):
//   A: [panel 256][kc 8][limb 2][slot 4][row 128][16B]  = 32 MB   (128 tokens/panel)
//   E: [panel 16 ][kc 8][limb 2][slot 4][row 128][16B]  =  2 MB   (128 codes/panel)
// NOTE (R3 lesson): do NOT stage these with global_load_lds — it defeated L2 reuse
// (FETCH 24MB -> 2.3GB). Regular loads + ds_write keep the 16x/256x panel reuse in L2/L3.

#define CDIM 256
#define KDIM 2048
#define HW   1024
#define NTOK 32768
#define QOFF 8388608
#define LOFF (QOFF + NTOK)

typedef _Float16 f16x8 __attribute__((ext_vector_type(8)));
typedef float    f32x4 __attribute__((ext_vector_type(4)));

// ---------------- prep E: limbs into panel image + scaled esq + loss ----------------
__global__ __launch_bounds__(256) void prep_e_kernel(const float* __restrict__ ew,
                                                     char* __restrict__ Ews,
                                                     float* __restrict__ esq,
                                                     float* __restrict__ out) {
    const int t = threadIdx.x;
    const int code = blockIdx.x * 8 + (t >> 5);   // 256 blocks x 8 codes
    const int u = t & 31;                          // 8-channel unit
    const float4 v0 = *(const float4*)&ew[(size_t)code * CDIM + u * 8];
    const float4 v1 = *(const float4*)&ew[(size_t)code * CDIM + u * 8 + 4];
    float s = v0.x*v0.x + v0.y*v0.y + v0.z*v0.z + v0.w*v0.w
            + v1.x*v1.x + v1.y*v1.y + v1.z*v1.z + v1.w*v1.w;
    #pragma unroll
    for (int m = 16; m >= 1; m >>= 1) s += __shfl_xor(s, m, 32);
    if (u == 0) esq[code] = s * 8192.0f;
    const float e[8] = {v0.x, v0.y, v0.z, v0.w, v1.x, v1.y, v1.z, v1.w};
    union { _Float16 h[8]; uint4 q; } H, L;
    #pragma unroll
    for (int j = 0; j < 8; ++j) {
        const float ev = e[j] * 8192.0f;
        const _Float16 hh = (_Float16)ev;
        H.h[j] = hh;
        L.h[j] = (_Float16)((ev - (float)hh) * 4096.0f);
    }
    const int kc = u >> 2, g = u & 3;
    const int cp = code >> 7, row = code & 127;
    char* d = Ews + (size_t)cp * 131072 + kc * 16384 + (g * 128 + row) * 16;
    *(uint4*)d = H.q;
    *(uint4*)(d + 8192) = L.q;
    if (blockIdx.x == 0 && t == 0) out[LOFF] = 0.0f;
}

// ---------------- prep X: transpose [C][HW] -> limb panel image ----------------
__global__ __launch_bounds__(256) void prep_x_kernel(const float* __restrict__ x,
                                                     char* __restrict__ Aws) {
    __shared__ float tile[32][257];
    const int bid = blockIdx.x;              // 32 b * 8 kc * 4 hwblk = 1024
    const int b = bid >> 5;
    const int kc = (bid >> 2) & 7;
    const int c0 = kc * 32;
    const int hw0 = (bid & 3) * 256;
    const int t = threadIdx.x;
    #pragma unroll 8
    for (int r = 0; r < 32; ++r)
        tile[r][t] = x[((size_t)(b * CDIM + c0 + r) << 10) + hw0 + t];
    __syncthreads();
    union { _Float16 h[32]; uint4 q[4]; } Hb, Lb;
    #pragma unroll 8
    for (int r = 0; r < 32; ++r) {
        const float xv = tile[r][t];
        const _Float16 hh = (_Float16)xv;
        Hb.h[r] = hh;
        Lb.h[r] = (_Float16)((xv - (float)hh) * 4096.0f);
    }
    const int tok = b * HW + hw0 + t;
    const int p = tok >> 7, row = tok & 127;
    char* d = Aws + (size_t)p * 131072 + kc * 16384 + row * 16;
    #pragma unroll
    for (int g = 0; g < 4; ++g) {
        *(uint4*)(d + g * 2048)        = Hb.q[g];   // high limb
        *(uint4*)(d + 8192 + g * 2048) = Lb.q[g];   // low limb
    }
}

// ---------------- fused MFMA GEMM + argmin ----------------
// 128x128 tile, 4 waves (2x2 of 64x64), BK=32, 32KB LDS, reg-staged, 3 blocks/CU.
__global__ __launch_bounds__(256, 3) void vqmm_kernel(const char* __restrict__ Aws,
                                                      const char* __restrict__ Ews,
                                                      const float* __restrict__ esq,
                                                      float* __restrict__ cv,
                                                      int* __restrict__ ci) {
    __shared__ __align__(16) char smem[32768];   // Ah 8K | Al 8K | Eh 8K | El 8K

    const int t = threadIdx.x;
    const int bid = blockIdx.x;
    // XCD-grouped swizzle: the 16 bx-blocks of one by share bid%8 -> same XCD (A panel L2-local)
    const int by = (bid & 7) | ((bid >> 7) << 3);   // token panel 0..255
    const int bx = (bid >> 3) & 15;                 // code panel 0..15
    const int lane = t & 63, w = t >> 6;
    const int wm = w >> 1, wn = w & 1;
    const int g = lane >> 4, lr = lane & 15;

    // staging role: wave 0->Ah, 1->Al, 2->Eh, 3->El; per chunk each thread moves 128B
    const char* src = ((w < 2) ? (Aws + (size_t)by * 131072) : (Ews + (size_t)bx * 131072))
                      + (w & 1) * 8192 + lane * 16;
    char* const dst = smem + w * 8192 + lane * 16;

    const f32x4 zf = {0.f, 0.f, 0.f, 0.f};
    f32x4 acc1[4][4], acc2[4][4];
    #pragma unroll
    for (int m = 0; m < 4; ++m)
        #pragma unroll
        for (int n = 0; n < 4; ++n) { acc1[m][n] = zf; acc2[m][n] = zf; }

    uint4 rg[8];
    // prologue: chunk 0 -> regs -> LDS
    #pragma unroll
    for (int j = 0; j < 8; ++j) rg[j] = *(const uint4*)(src + j * 1024);
    #pragma unroll
    for (int j = 0; j < 8; ++j) *(uint4*)(dst + j * 1024) = rg[j];
    __syncthreads();

    const int aro = (g * 128 + wm * 64 + lr) * 16;            // Ah frag base
    const int bro = 16384 + (g * 128 + wn * 64 + lr) * 16;    // Eh frag base

    for (int kc = 0; kc < 8; ++kc) {
        // R[kc]: fragments to registers
        f16x8 fa[4], fb[4], fc[4], fd[4];
        #pragma unroll
        for (int m = 0; m < 4; ++m) {
            fa[m] = *(const f16x8*)(smem + aro + m * 256);
            fb[m] = *(const f16x8*)(smem + 8192 + aro + m * 256);
        }
        #pragma unroll
        for (int n = 0; n < 4; ++n) {
            fc[n] = *(const f16x8*)(smem + bro + n * 256);
            fd[n] = *(const f16x8*)(smem + 8192 + bro + n * 256);
        }
        __syncthreads();           // all waves' reads of chunk kc retired (drains lgkm)
        // G[kc+1]: issue AFTER the barrier so the barrier's vmcnt(0) drain doesn't eat it;
        // the loads fly under the MFMA cluster below, consumed by the ds_write after it.
        if (kc < 7) {
            const char* s2 = src + (kc + 1) * 16384;
            #pragma unroll
            for (int j = 0; j < 8; ++j) rg[j] = *(const uint4*)(s2 + j * 1024);
        }
        // M[kc]: 48 MFMAs, register-only
        #pragma unroll
        for (int m = 0; m < 4; ++m)
            #pragma unroll
            for (int n = 0; n < 4; ++n) {
                acc1[m][n] = __builtin_amdgcn_mfma_f32_16x16x32_f16(fa[m], fc[n], acc1[m][n], 0, 0, 0);
                acc2[m][n] = __builtin_amdgcn_mfma_f32_16x16x32_f16(fa[m], fd[n], acc2[m][n], 0, 0, 0);
                acc2[m][n] = __builtin_amdgcn_mfma_f32_16x16x32_f16(fb[m], fc[n], acc2[m][n], 0, 0, 0);
            }
        // W[kc+1]: refill the buffer (implicit vmcnt wait on rg)
        if (kc < 7) {
            #pragma unroll
            for (int j = 0; j < 8; ++j) *(uint4*)(dst + j * 1024) = rg[j];
        }
        __syncthreads();           // chunk kc+1 visible to all (last iter: guards epilogue smem reuse)
    }

    // epilogue (reuses smem): esq[128] at 0, sv[128][2] at 1024, si[128][2] at 2048
    float* s_esq = (float*)smem;
    float* sv = (float*)(smem + 1024);
    int*   si = (int*)(smem + 2048);
    if (t < 128) s_esq[t] = esq[bx * 128 + t];
    __syncthreads();
    #pragma unroll
    for (int m = 0; m < 4; ++m) {
        #pragma unroll
        for (int r = 0; r < 4; ++r) {
            float bv = 3.4e38f; int bi = 0x7fffffff;
            #pragma unroll
            for (int n = 0; n < 4; ++n) {
                const float d = fmaf(-2.0f, acc1[m][n][r],
                                fmaf(-4.8828125e-4f, acc2[m][n][r], s_esq[wn * 64 + n * 16 + lr]));
                const int cidx = bx * 128 + wn * 64 + n * 16 + lr;
                if (d < bv) { bv = d; bi = cidx; }
            }
            #pragma unroll
            for (int mk = 1; mk < 16; mk <<= 1) {
                const float ov = __shfl_xor(bv, mk, 16);
                const int   oi = __shfl_xor(bi, mk, 16);
                if (ov < bv || (ov == bv && oi < bi)) { bv = ov; bi = oi; }
            }
            if (lr == 0) {
                const int tl = wm * 64 + m * 16 + g * 4 + r;
                sv[tl * 2 + wn] = bv; si[tl * 2 + wn] = bi;
            }
        }
    }
    __syncthreads();
    if (t < 128) {
        const float v0 = sv[t * 2], v1 = sv[t * 2 + 1];
        const int   i0 = si[t * 2], i1 = si[t * 2 + 1];
        const bool swp = (v1 < v0) || (v1 == v0 && i1 < i0);
        const size_t o = (size_t)bx * NTOK + by * 128 + t;
        cv[o] = swp ? v1 : v0;
        ci[o] = swp ? i1 : i0;
    }
}

// ---------------- merge 16 candidates + gather quantize ----------------
__global__ __launch_bounds__(256) void merge_gather_kernel(const float* __restrict__ cv,
                                                           const int* __restrict__ ci,
                                                           const float* __restrict__ ew,
                                                           float* __restrict__ out) {
    __shared__ int sIdx[64];
    const int t = threadIdx.x;
    const int n0 = blockIdx.x * 64;
    if (t < 64) {
        const int tok = n0 + t;
        float bv = cv[tok]; int bi = ci[tok];
        #pragma unroll
        for (int s = 1; s < 16; ++s) {
            const float v = cv[(size_t)s * NTOK + tok];
            const int   i2 = ci[(size_t)s * NTOK + tok];
            if (v < bv || (v == bv && i2 < bi)) { bv = v; bi = i2; }
        }
        sIdx[t] = bi;
        out[QOFF + tok] = (float)bi;
    }
    __syncthreads();
    const int b = n0 >> 10, hw0 = n0 & (HW - 1);
    const int i = t & 63, cg = t >> 6;
    const int kidx = sIdx[i];
    const float* er = ew + (size_t)kidx * CDIM;
    float* ob = out + (size_t)b * CDIM * HW + hw0 + i;
    #pragma unroll
    for (int p = 0; p < CDIM / 4; ++p) {
        const int c = cg * 64 + p;
        ob[(size_t)c * HW] = er[c];
    }
}

extern "C" void kernel_launch(void* const* d_in, const int* in_sizes, int n_in,
                              void* d_out, int out_size, void* d_ws, size_t ws_size,
                              hipStream_t stream) {
    const float* x  = (const float*)d_in[0];
    const float* ew = (const float*)d_in[1];
    float* out = (float*)d_out;
    char* ws = (char*)d_ws;

    char*  Aws = ws;                                // 33,554,432 B
    char*  Ews = ws + 33554432;                     //  2,097,152 B
    float* esq = (float*)(ws + 35651584);           //      8,192 B
    float* cvv = (float*)(ws + 35659776);           //  2,097,152 B
    int*   cii = (int*)(ws + 37756928);             //  2,097,152 B

    prep_e_kernel<<<KDIM / 8, 256, 0, stream>>>(ew, Ews, esq, out);
    prep_x_kernel<<<1024, 256, 0, stream>>>(x, Aws);
    vqmm_kernel<<<4096, 256, 0, stream>>>(Aws, Ews, esq, cvv, cii);
    merge_gather_kernel<<<NTOK / 64, 256, 0, stream>>>(cvv, cii, ew, out);
}

// Round 5
// 176.136 us; speedup vs baseline: 7.0475x; 1.9264x over previous
//
#include <hip/hip_runtime.h>

// VQ codebook assignment via split-f16 MFMA GEMM, pre-swizzled linear panels,
// reg-staged LDS double-buffer (1 barrier/chunk).
//   x:       [B=32, C=256, H=32, W=32] f32   -> tokens [32768][256]
//   embed_w: [K=2048, C=256] f32
// out f32: quantize [32,256,32,32] (8388608) | embed_index [32,32,32] (32768 as float) | loss [1]=0
//
// Math (verified R2-R4): e' = 8192*e; eh=f16(e'), el=f16((e'-eh)*4096); xh=f16(x), xl=f16((x-xh)*4096).
//   8192*dot = acc1 + acc2/4096,  acc1 = sum xh*eh, acc2 = sum(xh*el + xl*eh)
//   d' = 8192*esq - 2*acc1 - 2^-11*acc2 ; argmin_k d' == argmin_k (esq - 2 dot)  (err ~2^-24 rel)
//
// ws panel layout (linear LDS image, verified R3/R4):
//   A: [panel 256][kc 8][limb 2][slot 4][row 128][16B]  = 32 MB   (128 tokens/panel)
//   E: [panel 16 ][kc 8][limb 2][slot 4][row 128][16B]  =  2 MB   (128 codes/panel)
// R3 lesson: no global_load_lds here (kills L2 panel reuse: FETCH 24MB->2.3GB).
// R4 lesson: no launch_bounds below ~250 regs (spills: WRITE 4MB->809MB).

#define CDIM 256
#define KDIM 2048
#define HW   1024
#define NTOK 32768
#define QOFF 8388608
#define LOFF (QOFF + NTOK)

typedef _Float16 f16x8 __attribute__((ext_vector_type(8)));
typedef float    f32x4 __attribute__((ext_vector_type(4)));

// ---------------- prep E: limbs into panel image + scaled esq + loss ----------------
__global__ __launch_bounds__(256) void prep_e_kernel(const float* __restrict__ ew,
                                                     char* __restrict__ Ews,
                                                     float* __restrict__ esq,
                                                     float* __restrict__ out) {
    const int t = threadIdx.x;
    const int code = blockIdx.x * 8 + (t >> 5);   // 256 blocks x 8 codes
    const int u = t & 31;                          // 8-channel unit
    const float4 v0 = *(const float4*)&ew[(size_t)code * CDIM + u * 8];
    const float4 v1 = *(const float4*)&ew[(size_t)code * CDIM + u * 8 + 4];
    float s = v0.x*v0.x + v0.y*v0.y + v0.z*v0.z + v0.w*v0.w
            + v1.x*v1.x + v1.y*v1.y + v1.z*v1.z + v1.w*v1.w;
    #pragma unroll
    for (int m = 16; m >= 1; m >>= 1) s += __shfl_xor(s, m, 32);
    if (u == 0) esq[code] = s * 8192.0f;
    const float e[8] = {v0.x, v0.y, v0.z, v0.w, v1.x, v1.y, v1.z, v1.w};
    union { _Float16 h[8]; uint4 q; } H, L;
    #pragma unroll
    for (int j = 0; j < 8; ++j) {
        const float ev = e[j] * 8192.0f;
        const _Float16 hh = (_Float16)ev;
        H.h[j] = hh;
        L.h[j] = (_Float16)((ev - (float)hh) * 4096.0f);
    }
    const int kc = u >> 2, g = u & 3;
    const int cp = code >> 7, row = code & 127;
    char* d = Ews + (size_t)cp * 131072 + kc * 16384 + (g * 128 + row) * 16;
    *(uint4*)d = H.q;
    *(uint4*)(d + 8192) = L.q;
    if (blockIdx.x == 0 && t == 0) out[LOFF] = 0.0f;
}

// ---------------- prep X: transpose [C][HW] -> limb panel image ----------------
__global__ __launch_bounds__(256) void prep_x_kernel(const float* __restrict__ x,
                                                     char* __restrict__ Aws) {
    __shared__ float tile[32][257];
    const int bid = blockIdx.x;              // 32 b * 8 kc * 4 hwblk = 1024
    const int b = bid >> 5;
    const int kc = (bid >> 2) & 7;
    const int c0 = kc * 32;
    const int hw0 = (bid & 3) * 256;
    const int t = threadIdx.x;
    #pragma unroll 8
    for (int r = 0; r < 32; ++r)
        tile[r][t] = x[((size_t)(b * CDIM + c0 + r) << 10) + hw0 + t];
    __syncthreads();
    union { _Float16 h[32]; uint4 q[4]; } Hb, Lb;
    #pragma unroll 8
    for (int r = 0; r < 32; ++r) {
        const float xv = tile[r][t];
        const _Float16 hh = (_Float16)xv;
        Hb.h[r] = hh;
        Lb.h[r] = (_Float16)((xv - (float)hh) * 4096.0f);
    }
    const int tok = b * HW + hw0 + t;
    const int p = tok >> 7, row = tok & 127;
    char* d = Aws + (size_t)p * 131072 + kc * 16384 + row * 16;
    #pragma unroll
    for (int g = 0; g < 4; ++g) {
        *(uint4*)(d + g * 2048)        = Hb.q[g];   // high limb
        *(uint4*)(d + 8192 + g * 2048) = Lb.q[g];   // low limb
    }
}

// ---------------- fused MFMA GEMM + argmin ----------------
// 128x128 tile, 4 waves (2x2 of 64x64), BK=32, LDS dbuf 2x32KB, 1 barrier/chunk.
__global__ __launch_bounds__(256, 2) void vqmm_kernel(const char* __restrict__ Aws,
                                                      const char* __restrict__ Ews,
                                                      const float* __restrict__ esq,
                                                      float* __restrict__ cv,
                                                      int* __restrict__ ci) {
    __shared__ __align__(16) char smem[65536];   // buf0 | buf1, each: Ah 8K|Al 8K|Eh 8K|El 8K

    const int t = threadIdx.x;
    const int bid = blockIdx.x;
    // XCD-grouped swizzle: the 16 bx-blocks of one by share bid%8 -> same XCD (A panel L2-local)
    const int by = (bid & 7) | ((bid >> 7) << 3);   // token panel 0..255
    const int bx = (bid >> 3) & 15;                 // code panel 0..15
    const int lane = t & 63, w = t >> 6;
    const int wm = w >> 1, wn = w & 1;
    const int g = lane >> 4, lr = lane & 15;

    // staging role: wave 0->Ah, 1->Al, 2->Eh, 3->El; per chunk each thread moves 128B
    const char* src = ((w < 2) ? (Aws + (size_t)by * 131072) : (Ews + (size_t)bx * 131072))
                      + (w & 1) * 8192 + lane * 16;
    const int dsto = w * 8192 + lane * 16;

    const f32x4 zf = {0.f, 0.f, 0.f, 0.f};
    f32x4 acc1[4][4], acc2[4][4];
    #pragma unroll
    for (int m = 0; m < 4; ++m)
        #pragma unroll
        for (int n = 0; n < 4; ++n) { acc1[m][n] = zf; acc2[m][n] = zf; }

    uint4 rg[8];
    // prologue: chunk 0 -> regs -> buf0
    #pragma unroll
    for (int j = 0; j < 8; ++j) rg[j] = *(const uint4*)(src + j * 1024);
    #pragma unroll
    for (int j = 0; j < 8; ++j) *(uint4*)(smem + dsto + j * 1024) = rg[j];
    __syncthreads();

    const int aro = (g * 128 + wm * 64 + lr) * 16;            // Ah frag offset within buf
    const int bro = 16384 + (g * 128 + wn * 64 + lr) * 16;    // Eh frag offset within buf

    for (int kc = 0; kc < 8; ++kc) {
        const char* buf = smem + (kc & 1) * 32768;
        // G[kc+1]: issue first — latency hides under frag reads + MFMA below
        if (kc < 7) {
            const char* s2 = src + (kc + 1) * 16384;
            #pragma unroll
            for (int j = 0; j < 8; ++j) rg[j] = *(const uint4*)(s2 + j * 1024);
        }
        // R[kc]: fragments to registers
        f16x8 fa[4], fb[4], fc[4], fd[4];
        #pragma unroll
        for (int m = 0; m < 4; ++m) {
            fa[m] = *(const f16x8*)(buf + aro + m * 256);
            fb[m] = *(const f16x8*)(buf + 8192 + aro + m * 256);
        }
        #pragma unroll
        for (int n = 0; n < 4; ++n) {
            fc[n] = *(const f16x8*)(buf + bro + n * 256);
            fd[n] = *(const f16x8*)(buf + 8192 + bro + n * 256);
        }
        // M[kc]: 48 MFMAs, register-only
        #pragma unroll
        for (int m = 0; m < 4; ++m)
            #pragma unroll
            for (int n = 0; n < 4; ++n) {
                acc1[m][n] = __builtin_amdgcn_mfma_f32_16x16x32_f16(fa[m], fc[n], acc1[m][n], 0, 0, 0);
                acc2[m][n] = __builtin_amdgcn_mfma_f32_16x16x32_f16(fa[m], fd[n], acc2[m][n], 0, 0, 0);
                acc2[m][n] = __builtin_amdgcn_mfma_f32_16x16x32_f16(fb[m], fc[n], acc2[m][n], 0, 0, 0);
            }
        // W[kc+1]: write staged regs into the other buffer (safe: its readers
        // finished in iter kc-1 before that iter's barrier)
        if (kc < 7) {
            char* nb = smem + ((kc + 1) & 1) * 32768;
            #pragma unroll
            for (int j = 0; j < 8; ++j) *(uint4*)(nb + dsto + j * 1024) = rg[j];
        }
        __syncthreads();   // chunk kc+1 visible; also guards epilogue smem reuse after kc=7
    }

    // epilogue (reuses smem): esq[128] at 0, sv[128][2] at 1024, si[128][2] at 2048
    float* s_esq = (float*)smem;
    float* sv = (float*)(smem + 1024);
    int*   si = (int*)(smem + 2048);
    if (t < 128) s_esq[t] = esq[bx * 128 + t];
    __syncthreads();
    #pragma unroll
    for (int m = 0; m < 4; ++m) {
        #pragma unroll
        for (int r = 0; r < 4; ++r) {
            float bv = 3.4e38f; int bi = 0x7fffffff;
            #pragma unroll
            for (int n = 0; n < 4; ++n) {
                const float d = fmaf(-2.0f, acc1[m][n][r],
                                fmaf(-4.8828125e-4f, acc2[m][n][r], s_esq[wn * 64 + n * 16 + lr]));
                const int cidx = bx * 128 + wn * 64 + n * 16 + lr;
                if (d < bv) { bv = d; bi = cidx; }
            }
            #pragma unroll
            for (int mk = 1; mk < 16; mk <<= 1) {
                const float ov = __shfl_xor(bv, mk, 16);
                const int   oi = __shfl_xor(bi, mk, 16);
                if (ov < bv || (ov == bv && oi < bi)) { bv = ov; bi = oi; }
            }
            if (lr == 0) {
                const int tl = wm * 64 + m * 16 + g * 4 + r;
                sv[tl * 2 + wn] = bv; si[tl * 2 + wn] = bi;
            }
        }
    }
    __syncthreads();
    if (t < 128) {
        const float v0 = sv[t * 2], v1 = sv[t * 2 + 1];
        const int   i0 = si[t * 2], i1 = si[t * 2 + 1];
        const bool swp = (v1 < v0) || (v1 == v0 && i1 < i0);
        const size_t o = (size_t)bx * NTOK + by * 128 + t;
        cv[o] = swp ? v1 : v0;
        ci[o] = swp ? i1 : i0;
    }
}

// ---------------- merge 16 candidates + gather quantize ----------------
__global__ __launch_bounds__(256) void merge_gather_kernel(const float* __restrict__ cv,
                                                           const int* __restrict__ ci,
                                                           const float* __restrict__ ew,
                                                           float* __restrict__ out) {
    __shared__ int sIdx[64];
    const int t = threadIdx.x;
    const int n0 = blockIdx.x * 64;
    if (t < 64) {
        const int tok = n0 + t;
        float bv = cv[tok]; int bi = ci[tok];
        #pragma unroll
        for (int s = 1; s < 16; ++s) {
            const float v = cv[(size_t)s * NTOK + tok];
            const int   i2 = ci[(size_t)s * NTOK + tok];
            if (v < bv || (v == bv && i2 < bi)) { bv = v; bi = i2; }
        }
        sIdx[t] = bi;
        out[QOFF + tok] = (float)bi;
    }
    __syncthreads();
    const int b = n0 >> 10, hw0 = n0 & (HW - 1);
    const int i = t & 63, cg = t >> 6;
    const int kidx = sIdx[i];
    const float* er = ew + (size_t)kidx * CDIM;
    float* ob = out + (size_t)b * CDIM * HW + hw0 + i;
    #pragma unroll
    for (int p = 0; p < CDIM / 4; ++p) {
        const int c = cg * 64 + p;
        ob[(size_t)c * HW] = er[c];
    }
}

extern "C" void kernel_launch(void* const* d_in, const int* in_sizes, int n_in,
                              void* d_out, int out_size, void* d_ws, size_t ws_size,
                              hipStream_t stream) {
    const float* x  = (const float*)d_in[0];
    const float* ew = (const float*)d_in[1];
    float* out = (float*)d_out;
    char* ws = (char*)d_ws;

    char*  Aws = ws;                                // 33,554,432 B
    char*  Ews = ws + 33554432;                     //  2,097,152 B
    float* esq = (float*)(ws + 35651584);           //      8,192 B
    float* cvv = (float*)(ws + 35659776);           //  2,097,152 B
    int*   cii = (int*)(ws + 37756928);             //  2,097,152 B

    prep_e_kernel<<<KDIM / 8, 256, 0, stream>>>(ew, Ews, esq, out);
    prep_x_kernel<<<1024, 256, 0, stream>>>(x, Aws);
    vqmm_kernel<<<4096, 256, 0, stream>>>(Aws, Ews, esq, cvv, cii);
    merge_gather_kernel<<<NTOK / 64, 256, 0, stream>>>(cvv, cii, ew, out);
}